// Round 1
// 156.698 us; speedup vs baseline: 1.0033x; 1.0033x over previous
//
#include <hip/hip_runtime.h>
#include <math.h>

#define N_EXC   20000
#define N_KCC   1024
#define FDIM    128
#define LEAKY_S 0.2f
#define LOG2E   1.44269504f

#define BR  32       // exercise rows per block
#define TJ  128      // kc (j) tile (8 tiles)
#define EXS 136      // ex/w LDS stride in ushorts (272 B: 2-way-free for b128)

typedef unsigned short ushort_t;
typedef __attribute__((ext_vector_type(8))) short short8;
typedef __attribute__((ext_vector_type(4))) float floatx4;

__device__ __forceinline__ ushort_t f2bf(float f) {
    unsigned u = __float_as_uint(f);
    u += 0x7FFF + ((u >> 16) & 1);          // RNE
    return (ushort_t)(u >> 16);
}

// async global->LDS, 16 B per lane. LDS dest must be wave-uniform base + lane*16.
__device__ __forceinline__ void async16(const void* g, void* l) {
    __builtin_amdgcn_global_load_lds(
        (const __attribute__((address_space(1))) unsigned int*)g,
        (__attribute__((address_space(3))) unsigned int*)l,
        16, 0, 0);
}

// ws layout (float offsets):
//   [0)     tarr  1024 f32 — t2[j] = (kc[j]·(W1 a2))·LOG2E  (exp2 domain)
//   [1024)  w1a1  128 f32  — (W1 a1)·LOG2E
//   [1152)  tmax4 4 f32 (+4 pad) — per-t-block max of t2
//   [1160)  kc_sw 131072 ushorts (256 KB): 8 tiles x [f=128][c'=16][e=8],
//           c' = (j_loc>>3) ^ (f&15), value = bf16(kcWh[j][f])
//   [+256K) E_sw  16384 ushorts (32 KB): [n=128][c'=16][e=8],
//           c' = (k>>3) ^ (n&15), value = bf16(E[k][n])
#define WS_TMAX (N_KCC + FDIM)        // 1152
#define WS_KC   (N_KCC + FDIM + 8)    // 1160 floats = 4640 B, 16B aligned

__global__ __launch_bounds__(256) void gat_prep(const float* __restrict__ kc_h,
                                                const float* __restrict__ W1,
                                                const float* __restrict__ E,
                                                const float* __restrict__ a,
                                                float* __restrict__ ws)
{
    float* tarr  = ws;
    float* w1a1  = ws + N_KCC;
    float* tmax4 = ws + WS_TMAX;
    ushort_t* kc_sw = (ushort_t*)(ws + WS_KC);
    ushort_t* E_sw  = kc_sw + FDIM * N_KCC;
    const int tid = threadIdx.x;
    const int b = blockIdx.x;

    __shared__ __align__(16) float kct[128 * 132];     // 67.6 KB
    __shared__ __align__(16) ushort_t sw[32 * 128];    // 8 KB
    __shared__ __align__(16) float w1a2_lds[FDIM];
    __shared__ float redm[4];

    if (b < 32) {
        // kcWh tile: j-tile jb (128 rows), f-quarter fq (32 cols)
        const int jb = b >> 2, fq = b & 3;
        const float* kcbase = kc_h + (size_t)jb * 128 * FDIM;
        #pragma unroll
        for (int u = 0; u < 16; ++u) {
            int flat = u * 256 + tid;
            int r = flat >> 5, c4 = (flat & 31) * 4;
            float4 v = *(const float4*)(kcbase + r * FDIM + c4);
            kct[r * 132 + c4 + 0] = v.x; kct[r * 132 + c4 + 1] = v.y;
            kct[r * 132 + c4 + 2] = v.z; kct[r * 132 + c4 + 3] = v.w;
        }
        __syncthreads();
        const int jg = tid >> 4;                 // j rows jg*8..+7
        const int fg = tid & 15;                 // 2 f cols
        const int f0 = fq * 32 + fg * 2;
        float acc[8][2];
        #pragma unroll
        for (int i = 0; i < 8; ++i) { acc[i][0] = 0.f; acc[i][1] = 0.f; }
        for (int k4 = 0; k4 < FDIM; k4 += 4) {
            float4 av[8];
            #pragma unroll
            for (int i = 0; i < 8; ++i)
                av[i] = *(const float4*)(kct + (jg * 8 + i) * 132 + k4);
            #pragma unroll
            for (int kk = 0; kk < 4; ++kk) {
                float2 bv = *(const float2*)(W1 + (k4 + kk) * FDIM + f0);
                #pragma unroll
                for (int i = 0; i < 8; ++i) {
                    float a_ = ((const float*)&av[i])[kk];
                    acc[i][0] += a_ * bv.x;
                    acc[i][1] += a_ * bv.y;
                }
            }
        }
        // pack 8 e per (f) into uint4, swizzled chunk c' = jg ^ (f&15)
        #pragma unroll
        for (int c = 0; c < 2; ++c) {
            int f = f0 + c;
            int fl = fg * 2 + c;
            unsigned pk[4];
            #pragma unroll
            for (int i = 0; i < 4; ++i)
                pk[i] = (unsigned)f2bf(acc[2 * i][c]) | ((unsigned)f2bf(acc[2 * i + 1][c]) << 16);
            int cp = jg ^ (f & 15);
            *(uint4*)(sw + fl * 128 + cp * 8) = make_uint4(pk[0], pk[1], pk[2], pk[3]);
        }
        __syncthreads();
        ushort_t* dst = kc_sw + ((size_t)jb * 128 + fq * 32) * 128;
        #pragma unroll
        for (int u = 0; u < 2; ++u) {
            int flat = u * 256 + tid;
            *(uint4*)(dst + flat * 8) = *(const uint4*)(sw + flat * 8);
        }
        return;
    }

    if (b < 36) {
        // t2[j] = (kc[j] . (W1 @ a2)) * LOG2E; block 32 also writes w1a1*LOG2E
        if (tid >= 128) {
            int k = tid - 128;
            float acc = 0.f;
            const float* row = W1 + k * FDIM;
            #pragma unroll 8
            for (int f = 0; f < FDIM; ++f) acc += row[f] * a[FDIM + f];
            w1a2_lds[k] = acc;
        } else if (b == 32) {
            float acc = 0.f;
            const float* row = W1 + tid * FDIM;
            #pragma unroll 8
            for (int f = 0; f < FDIM; ++f) acc += row[f] * a[f];
            w1a1[tid] = acc * LOG2E;             // pre-scaled: main's s is in exp2 domain
        }
        __syncthreads();
        int j = (b - 32) * 256 + tid;
        float s = 0.f;
        #pragma unroll 8
        for (int c = 0; c < 32; ++c) {
            float4 v = *(const float4*)(kc_h + (size_t)j * FDIM + c * 4);
            s += v.x * w1a2_lds[c * 4 + 0] + v.y * w1a2_lds[c * 4 + 1]
               + v.z * w1a2_lds[c * 4 + 2] + v.w * w1a2_lds[c * 4 + 3];
        }
        float t2 = s * LOG2E;
        tarr[j] = t2;
        // block-level max(t2) -> tmax4[b-32]; main reads 4 floats instead of
        // doing a 1024-wide reduce per block (x625 blocks).
        float bm = t2;
        #pragma unroll
        for (int off = 32; off; off >>= 1) bm = fmaxf(bm, __shfl_xor(bm, off));
        if ((tid & 63) == 0) redm[tid >> 6] = bm;
        __syncthreads();
        if (tid == 0)
            tmax4[b - 32] = fmaxf(fmaxf(redm[0], redm[1]), fmaxf(redm[2], redm[3]));
        return;
    }

    // b == 36: E_sw swizzled bf16
    #pragma unroll
    for (int u = 0; u < 8; ++u) {
        int ch = u * 256 + tid;          // 2048 chunks
        int n = ch >> 4, cp = ch & 15;
        int c = cp ^ (n & 15);
        unsigned pk[4];
        #pragma unroll
        for (int i = 0; i < 4; ++i) {
            float e0 = E[(c * 8 + 2 * i + 0) * FDIM + n];
            float e1 = E[(c * 8 + 2 * i + 1) * FDIM + n];
            pk[i] = (unsigned)f2bf(e0) | ((unsigned)f2bf(e1) << 16);
        }
        *(uint4*)(E_sw + ch * 8) = make_uint4(pk[0], pk[1], pk[2], pk[3]);
    }
}

__global__ __launch_bounds__(256, 3) void gat_main(const float* __restrict__ ex_h,
                                                   const int* __restrict__ adj,
                                                   const float* __restrict__ ws,
                                                   float* __restrict__ out)
{
    const float* tarr  = ws;
    const float* w1a1  = ws + N_KCC;
    const float* tmax4 = ws + WS_TMAX;
    const ushort_t* kc_sw = (const ushort_t*)(ws + WS_KC);
    const ushort_t* E_sw  = kc_sw + FDIM * N_KCC;

    __shared__ __align__(16) float t_lds[N_KCC];            // 4 KB (t2, exp2 domain)
    __shared__ __align__(16) ushort_t kc_lds[FDIM * TJ];    // 32 KB (E, then kc tiles)
    __shared__ __align__(16) ushort_t exw_lds[BR * EXS];    // 8.7 KB (ex, then w)
    __shared__ __align__(16) float scrA[256];
    __shared__ float w1a1_lds[FDIM];
    __shared__ float a_lds[BR], b_lds[BR], denom_lds[BR];

    const int tid  = threadIdx.x;
    const int R0   = blockIdx.x * BR;
    const int lane = tid & 63, wid = tid >> 6;
    const int l15  = lane & 15, quad = lane >> 4;

    // ---- issue E async load first (32 KB) ----
    #pragma unroll
    for (int u = 0; u < 8; ++u) {
        int ci = u * 256 + tid;
        async16(E_sw + ci * 8, kc_lds + ci * 8);
    }

    // ---- stage t2, w1a1, ex rows ----
    #pragma unroll
    for (int u = 0; u < 4; ++u) t_lds[u * 256 + tid] = tarr[u * 256 + tid];
    if (tid < FDIM) w1a1_lds[tid] = w1a1[tid];
    const int r0 = tid >> 3;
    const int fc = (tid & 7) * 16;
    float exv[16];
    {
        const float* src = ex_h + (size_t)(R0 + r0) * FDIM + fc;
        #pragma unroll
        for (int c = 0; c < 4; ++c) {
            float4 v = *(const float4*)(src + c * 4);
            exv[c * 4 + 0] = v.x; exv[c * 4 + 1] = v.y;
            exv[c * 4 + 2] = v.z; exv[c * 4 + 3] = v.w;
        }
        unsigned pk[8];
        #pragma unroll
        for (int i = 0; i < 8; ++i)
            pk[i] = (unsigned)f2bf(exv[2 * i]) | ((unsigned)f2bf(exv[2 * i + 1]) << 16);
        *(uint4*)(exw_lds + r0 * EXS + fc)     = make_uint4(pk[0], pk[1], pk[2], pk[3]);
        *(uint4*)(exw_lds + r0 * EXS + fc + 8) = make_uint4(pk[4], pk[5], pk[6], pk[7]);
    }
    __syncthreads();   // drains E async + LDS writes

    // ---- s partials (s is already x LOG2E via pre-scaled w1a1) ----
    {
        float p = 0.f;
        #pragma unroll
        for (int i = 0; i < 16; ++i) p += exv[i] * w1a1_lds[fc + i];
        scrA[tid] = p;
    }
    __syncthreads();
    if (tid < BR) {
        float s2 = 0.f;
        #pragma unroll
        for (int g = 0; g < 8; ++g) s2 += scrA[tid * 8 + g];
        float Tm2 = fmaxf(fmaxf(tmax4[0], tmax4[1]), fmaxf(tmax4[2], tmax4[3]));
        float x2 = s2 + Tm2;
        float m2 = fmaxf(x2, LEAKY_S * x2);      // row max bound, exp2 domain
        a_lds[tid] = s2 - m2;                    // arg = max(a + t2, fma(t2, 0.2, b))
        b_lds[tid] = fmaf(s2, LEAKY_S, -m2);
    }
    __syncthreads();   // publish a_lds/b_lds to all waves

    // per-thread w-gen constants (LDS reads, after publish barrier)
    const int r_w = tid >> 3;          // w-gen row
    const int jg  = tid & 7;           // 16-j chunk within tile
    const float ar = a_lds[r_w];
    const float br = b_lds[r_w];
    float denom_part = 0.f;
    const int* aptr = adj + (size_t)(R0 + r_w) * N_KCC + jg * 16;

    // adj tile-0 prefetch: issued AFTER the last full-drain __syncthreads, so it
    // stays in flight through the raw barriers below (hidden under Eh MFMA).
    int4 cur0 = *(const int4*)(aptr + 0);
    int4 cur1 = *(const int4*)(aptr + 4);
    int4 cur2 = *(const int4*)(aptr + 8);
    int4 cur3 = *(const int4*)(aptr + 12);

    // ---- Eh = ex @ E via MFMA (E already in kc_lds, swizzled) ----
    floatx4 eh_acc[2][2], att_acc[2][2];
    #pragma unroll
    for (int mg = 0; mg < 2; ++mg)
        #pragma unroll
        for (int h = 0; h < 2; ++h) {
            eh_acc[mg][h]  = (floatx4){0.f, 0.f, 0.f, 0.f};
            att_acc[mg][h] = (floatx4){0.f, 0.f, 0.f, 0.f};
        }
    #pragma unroll
    for (int kk = 0; kk < 4; ++kk) {
        short8 a0 = *(const short8*)(exw_lds + l15 * EXS + kk * 32 + quad * 8);
        short8 a1 = *(const short8*)(exw_lds + (16 + l15) * EXS + kk * 32 + quad * 8);
        #pragma unroll
        for (int h = 0; h < 2; ++h) {
            const int n = (h * 4 + wid) * 16 + l15;
            const int cp = (kk * 4 + quad) ^ l15;
            short8 bf = *(const short8*)(kc_lds + n * TJ + cp * 8);
            eh_acc[0][h] = __builtin_amdgcn_mfma_f32_16x16x32_bf16(a0, bf, eh_acc[0][h], 0, 0, 0);
            eh_acc[1][h] = __builtin_amdgcn_mfma_f32_16x16x32_bf16(a1, bf, eh_acc[1][h], 0, 0, 0);
        }
    }

    // ---- main j loop: 8 tiles of 128, raw barriers + counted vmcnt ----
    // Steady-state vmem FIFO per thread: [4 adj (oldest)] [8 kc asyncs] [4 adj next].
    // vmcnt(4) before barrier B drains the asyncs but keeps next-tile adj in
    // flight ACROSS both barriers (~900+ cy of cover for the HBM-cold load).
    for (int jt = 0; jt < N_KCC / TJ; ++jt) {
        const int j0 = jt * TJ;
        asm volatile("" ::: "memory");
        __builtin_amdgcn_s_barrier();      // A: all MFMA ds_reads of prev tile retired
        // async stage kc tile (32 KB, pre-swizzled contiguous)
        {
            const ushort_t* gsrc = kc_sw + (size_t)jt * (FDIM * TJ);
            #pragma unroll
            for (int u = 0; u < 8; ++u) {
                int ci = u * 256 + tid;
                async16(gsrc + ci * 8, kc_lds + ci * 8);
            }
        }
        asm volatile("" ::: "memory");     // pin FIFO order: asyncs BEFORE adj prefetch
        // w generation: 16 j per thread; exp2-domain: 6 VALU ops/element
        {
            const int jb = j0 + jg * 16;
            int av[16] = {cur0.x, cur0.y, cur0.z, cur0.w, cur1.x, cur1.y, cur1.z, cur1.w,
                          cur2.x, cur2.y, cur2.z, cur2.w, cur3.x, cur3.y, cur3.z, cur3.w};
            float wv[16];
            #pragma unroll
            for (int c = 0; c < 4; ++c) {
                float4 t4 = *(const float4*)(t_lds + jb + c * 4);
                float tv[4] = {t4.x, t4.y, t4.z, t4.w};
                #pragma unroll
                for (int e = 0; e < 4; ++e) {
                    float t2 = tv[e];
                    float arg = fmaxf(ar + t2, fmaf(t2, LEAKY_S, br));
                    float w = exp2f(arg);
                    w = (av[c * 4 + e] > 0) ? w : 0.f;
                    denom_part += w;
                    wv[c * 4 + e] = w;
                }
            }
            // next-tile adj prefetch (wrap at jt=7: distinct address, no CSE)
            {
                int jn = ((jt + 1) & 7) * TJ;
                cur0 = *(const int4*)(aptr + jn + 0);
                cur1 = *(const int4*)(aptr + jn + 4);
                cur2 = *(const int4*)(aptr + jn + 8);
                cur3 = *(const int4*)(aptr + jn + 12);
            }
            unsigned pk[8];
            #pragma unroll
            for (int i = 0; i < 8; ++i) {
                unsigned ua = __float_as_uint(wv[2 * i + 0]) + 0x8000u;
                unsigned ub = __float_as_uint(wv[2 * i + 1]) + 0x8000u;
                pk[i] = __builtin_amdgcn_perm(ub, ua, 0x07060302);  // bf16 pair
            }
            *(uint4*)(exw_lds + r_w * EXS + jg * 16)     = make_uint4(pk[0], pk[1], pk[2], pk[3]);
            *(uint4*)(exw_lds + r_w * EXS + jg * 16 + 8) = make_uint4(pk[4], pk[5], pk[6], pk[7]);
        }
        // drain kc asyncs + w writes, KEEP next-tile adj in flight
        asm volatile("s_waitcnt vmcnt(4) lgkmcnt(0)" ::: "memory");
        __builtin_amdgcn_s_barrier();      // B: kc tile + w ready for all waves
        // MFMA: att += w[32 x 128] @ kcWh_tile[128 x 128]
        __builtin_amdgcn_s_setprio(1);
        #pragma unroll
        for (int kk = 0; kk < 4; ++kk) {
            short8 a0 = *(const short8*)(exw_lds + l15 * EXS + kk * 32 + quad * 8);
            short8 a1 = *(const short8*)(exw_lds + (16 + l15) * EXS + kk * 32 + quad * 8);
            #pragma unroll
            for (int h = 0; h < 2; ++h) {
                const int f = (h * 4 + wid) * 16 + l15;
                const int cp = (kk * 4 + quad) ^ l15;
                short8 bf = *(const short8*)(kc_lds + f * TJ + cp * 8);
                att_acc[0][h] = __builtin_amdgcn_mfma_f32_16x16x32_bf16(a0, bf, att_acc[0][h], 0, 0, 0);
                att_acc[1][h] = __builtin_amdgcn_mfma_f32_16x16x32_bf16(a1, bf, att_acc[1][h], 0, 0, 0);
            }
        }
        __builtin_amdgcn_s_setprio(0);
    }

    // ---- denominator reduce ----
    __syncthreads();   // full drain (incl. the dead wrap-around adj prefetch)
    scrA[tid] = denom_part;
    __syncthreads();
    if (tid < BR) {
        float d = 0.f;
        #pragma unroll
        for (int g = 0; g < 8; ++g) d += scrA[tid * 8 + g];
        denom_lds[tid] = (d > 0.f) ? d : 1.f;
    }
    __syncthreads();

    // ---- epilogue: normalize * Eh, elu, store (C-layout: col=l15, row=quad*4+reg) ----
    #pragma unroll
    for (int mg = 0; mg < 2; ++mg) {
        float rd[4];
        #pragma unroll
        for (int reg = 0; reg < 4; ++reg)
            rd[reg] = 1.f / denom_lds[mg * 16 + quad * 4 + reg];
        #pragma unroll
        for (int h = 0; h < 2; ++h) {
            const int col = (h * 4 + wid) * 16 + l15;
            #pragma unroll
            for (int reg = 0; reg < 4; ++reg) {
                const int rl = mg * 16 + quad * 4 + reg;
                float v = att_acc[mg][h][reg] * rd[reg] * eh_acc[mg][h][reg];
                out[(size_t)(R0 + rl) * FDIM + col] = (v > 0.f) ? v : expm1f(v);
            }
        }
    }
}

extern "C" void kernel_launch(void* const* d_in, const int* in_sizes, int n_in,
                              void* d_out, int out_size, void* d_ws, size_t ws_size,
                              hipStream_t stream)
{
    const float* ex_h = (const float*)d_in[0];
    const float* kc_h = (const float*)d_in[1];
    const int*   adj  = (const int*)d_in[2];
    const float* W1   = (const float*)d_in[3];
    const float* E    = (const float*)d_in[4];
    const float* a    = (const float*)d_in[5];
    float* outp = (float*)d_out;
    float* ws   = (float*)d_ws;

    gat_prep<<<37, 256, 0, stream>>>(kc_h, W1, E, a, ws);
    gat_main<<<N_EXC / BR, 256, 0, stream>>>(ex_h, adj, ws, outp);
}